// Round 4
// baseline (10133.960 us; speedup 1.0000x reference)
//
#include <hip/hip_runtime.h>

typedef _Float16 f16x8 __attribute__((ext_vector_type(8)));
typedef float    f32x4 __attribute__((ext_vector_type(4)));
typedef unsigned long long u64;

constexpr int BATCH = 1024;
constexpr int HDIM  = 512;
constexpr int TENC  = 512;
constexpr int PRED  = 48;
constexpr int STEPS = TENC + PRED - 1;   // 559 cell steps
constexpr int NGRP  = 32;                // independent batch groups
constexpr int GBAT  = 32;                // batches per group
constexpr int NUB   = 8;                 // unit-blocks per group
constexpr int UBU   = 64;                // units per block
constexpr int HB_OFF = 4096;             // hbuf offset in ws (bytes)

struct __align__(64) Bar { int count; int gen; int pad[14]; };

__global__ void init_kernel(int* wsi, float* out) {
  int idx = blockIdx.x * blockDim.x + threadIdx.x;
  int stride = gridDim.x * blockDim.x;
  const int nws = (HB_OFF + BATCH * HDIM * 2) / 4;  // bars + hbuf[0]
  for (int i = idx; i < nws; i += stride) wsi[i] = 0;
  for (int i = idx; i < BATCH * PRED; i += stride) out[i] = 0.f;
}

// 512 threads = 8 waves = 2 waves/SIMD. Wave pair (w, w^4): same 16-unit
// n-tile (tile = w&3), K split (half = w>>2 picks kc 0..7 or 8..15).
// After partial GEMM, pair exchanges the complementary m-tile partials via
// LDS; wave `half` then owns m-tile mt=half end-to-end (epilogue = 4 cells).
__global__ __launch_bounds__(512, 2) void lstm_persist(
    const float* __restrict__ x,
    const float* __restrict__ w_ih,
    const float* __restrict__ w_hh,
    const float* __restrict__ b_ih,
    const float* __restrict__ b_hh,
    const float* __restrict__ w_fc,
    const float* __restrict__ b_fc,
    float* __restrict__ out,          // [1024][48] fp32; also decode input
    _Float16* __restrict__ hbuf,      // [2][1024][512] fp16 ping-pong
    Bar* __restrict__ bars)           // [32] group barriers
{
  const int bid  = blockIdx.x;
  const int grp  = bid & (NGRP - 1);  // group's 8 blocks on one XCD (perf only)
  const int ub   = bid >> 5;
  const int tid  = threadIdx.x;
  const int wid  = tid >> 6;          // 0..7
  const int tile = wid & 3;           // n-tile (16 units)
  const int half = wid >> 2;          // k-half AND owned m-tile
  const int lane = tid & 63;
  const int quad = lane >> 4;
  const int lcol = lane & 15;
  const int b0   = grp * GBAT;
  const int myu  = ub * UBU + tile * 16 + lcol;

  __shared__ __align__(16) _Float16 hs[GBAT][520];   // 33.3 KB
  __shared__ f32x4 red[8][64][4];                    // 32 KB pair-exchange

  // ---- one-time: weight B-frags for this wave's kc half (128 VGPR) ----
  f16x8 wf[4][8];
  float wih[4], bias[4];
#pragma unroll
  for (int nt = 0; nt < 4; ++nt) {
    const int j = nt * HDIM + myu;
    wih[nt]  = w_ih[j];
    bias[nt] = b_ih[j] + b_hh[j];
#pragma unroll
    for (int kc = 0; kc < 8; ++kc) {
      const int kcg = half * 8 + kc;
      const float* s = w_hh + (size_t)j * HDIM + kcg * 32 + quad * 8;
      f16x8 v;
#pragma unroll
      for (int i = 0; i < 8; ++i) v[i] = (_Float16)s[i];
      wf[nt][kc] = v;
    }
  }
  const float wfc = w_fc[myu];
  const float bfc = b_fc[0];

  float cst[4];                        // 4 cells/lane (own m-tile)
#pragma unroll
  for (int r = 0; r < 4; ++r) cst[r] = 0.f;

  Bar* bar = &bars[grp];

  for (int t = 0; t < STEPS; ++t) {
    const _Float16* hcur = hbuf + (size_t)(t & 1) * BATCH * HDIM;
    _Float16*       hnxt = hbuf + (size_t)((t + 1) & 1) * BATCH * HDIM;

    // ---- x_t for own m-tile (decode feedback needs coherent load) ----
    float xts[4];
#pragma unroll
    for (int r = 0; r < 4; ++r) {
      const int b = b0 + half * 16 + quad * 4 + r;
      xts[r] = (t < TENC)
          ? x[(size_t)b * TENC + t]
          : __hip_atomic_load(&out[b * PRED + (t - TENC)],
                              __ATOMIC_RELAXED, __HIP_MEMORY_SCOPE_AGENT);
    }

    // ---- stage h tile into LDS (coherent 8B loads, all 8 in flight) ----
    u64 tmp[8];
#pragma unroll
    for (int i = 0; i < 8; ++i) {
      const int e   = tid + i * 512;      // 4096 8B-chunks
      const int row = e >> 7;
      const int c   = e & 127;
      tmp[i] = __hip_atomic_load(
          (const u64*)(hcur + (size_t)(b0 + row) * HDIM) + c,
          __ATOMIC_RELAXED, __HIP_MEMORY_SCOPE_AGENT);
    }
#pragma unroll
    for (int i = 0; i < 8; ++i) {
      const int e   = tid + i * 512;
      const int row = e >> 7;
      const int c   = e & 127;
      *reinterpret_cast<u64*>(&hs[row][c * 4]) = tmp[i];
    }
    __syncthreads();

    // ---- partial GEMM over this wave's kc half ----
    f32x4 acc[2][4];
#pragma unroll
    for (int mt = 0; mt < 2; ++mt)
#pragma unroll
      for (int nt = 0; nt < 4; ++nt) acc[mt][nt] = (f32x4){0.f, 0.f, 0.f, 0.f};

#pragma unroll
    for (int kc = 0; kc < 8; ++kc) {
      const int kcg = half * 8 + kc;
      f16x8 a0 = *reinterpret_cast<const f16x8*>(&hs[lcol][kcg * 32 + quad * 8]);
      f16x8 a1 = *reinterpret_cast<const f16x8*>(&hs[16 + lcol][kcg * 32 + quad * 8]);
#pragma unroll
      for (int nt = 0; nt < 4; ++nt) {
        acc[0][nt] = __builtin_amdgcn_mfma_f32_16x16x32_f16(a0, wf[nt][kc], acc[0][nt], 0, 0, 0);
        acc[1][nt] = __builtin_amdgcn_mfma_f32_16x16x32_f16(a1, wf[nt][kc], acc[1][nt], 0, 0, 0);
      }
    }

    // ---- pair exchange: give partner the m-tile it owns ----
#pragma unroll
    for (int nt = 0; nt < 4; ++nt) red[wid][lane][nt] = acc[half ^ 1][nt];
    __syncthreads();
    f32x4 accf[4];
#pragma unroll
    for (int nt = 0; nt < 4; ++nt)
      accf[nt] = acc[half][nt] + red[wid ^ 4][lane][nt];

    // ---- cell update: 4 cells/lane (C-layout col=lcol, row=quad*4+r) ----
    float hnew[4];
#pragma unroll
    for (int r = 0; r < 4; ++r) {
      const float xt = xts[r];
      const float gi = accf[0][r] + xt * wih[0] + bias[0];
      const float gf = accf[1][r] + xt * wih[1] + bias[1];
      const float gg = accf[2][r] + xt * wih[2] + bias[2];
      const float go = accf[3][r] + xt * wih[3] + bias[3];
      const float si = 1.f / (1.f + __expf(-gi));
      const float sf = 1.f / (1.f + __expf(-gf));
      const float so = 1.f / (1.f + __expf(-go));
      const float tg = 1.f - 2.f / (1.f + __expf(2.f * gg));
      const float cn = sf * cst[r] + si * tg;
      cst[r] = cn;
      const float tc = 1.f - 2.f / (1.f + __expf(2.f * cn));
      const float hn = so * tc;
      hnew[r] = hn;

      // pack 4 adjacent units across lanes -> one 8B coherent store
      const unsigned short hb = __builtin_bit_cast(unsigned short, (_Float16)hn);
      const unsigned v0  = hb;
      const unsigned o0  = (unsigned)__shfl_xor((int)v0, 1);
      const unsigned p01 = (lcol & 1) ? ((v0 << 16) | o0) : ((o0 << 16) | v0);
      const unsigned q   = (unsigned)__shfl_xor((int)p01, 2);
      const u64 p4 = (lcol & 2) ? (((u64)p01 << 32) | (u64)q)
                                : (((u64)q << 32) | (u64)p01);
      if ((lcol & 3) == r) {
        const int b = b0 + half * 16 + quad * 4 + r;
        _Float16* dst = hnxt + (size_t)b * HDIM + (ub * UBU + tile * 16 + (lcol & ~3));
        __hip_atomic_store((u64*)dst, p4, __ATOMIC_RELAXED, __HIP_MEMORY_SCOPE_AGENT);
      }
    }

    // ---- fc(h) for decode steps (must land before barrier arrival) ----
    if (t >= TENC - 1) {
      const int p = t - (TENC - 1);
#pragma unroll
      for (int r = 0; r < 4; ++r) {
        float v = hnew[r] * wfc;
        v += __shfl_xor(v, 1);
        v += __shfl_xor(v, 2);
        v += __shfl_xor(v, 4);
        v += __shfl_xor(v, 8);
        if (lcol == 0) {
          const int b = b0 + half * 16 + quad * 4 + r;
          // bias: exactly once per batch — contributed by the (ub0,tile0)
          // wave of WHICHEVER half owns this batch's m-tile (R3 bug: had
          // `&& half==0`, so half=1 batches never got b_fc -> absmax 3.3e-2)
          const float add = v + ((ub == 0 && tile == 0) ? bfc : 0.f);
          atomicAdd(&out[b * PRED + p], add);
        }
      }
    }

    // ---- group barrier: block-level arrival, wave-level wait ----
    asm volatile("s_waitcnt vmcnt(0)" ::: "memory");  // own stores drained
    __syncthreads();
    if (tid == 0) {
      int old = __hip_atomic_fetch_add(&bar->count, 1, __ATOMIC_RELAXED,
                                       __HIP_MEMORY_SCOPE_AGENT);
      if (old == NUB - 1) {
        __hip_atomic_store(&bar->count, 0, __ATOMIC_RELAXED, __HIP_MEMORY_SCOPE_AGENT);
        asm volatile("s_waitcnt vmcnt(0)" ::: "memory");
        __hip_atomic_fetch_add(&bar->gen, 1, __ATOMIC_RELAXED, __HIP_MEMORY_SCOPE_AGENT);
      }
    }
    // each wave waits independently (no block sync on the wait side)
    if (lane == 0) {
      while (__hip_atomic_load(&bar->gen, __ATOMIC_RELAXED,
                               __HIP_MEMORY_SCOPE_AGENT) < t + 1)
        __builtin_amdgcn_s_sleep(1);
    }
    __builtin_amdgcn_wave_barrier();
  }
}

extern "C" void kernel_launch(void* const* d_in, const int* in_sizes, int n_in,
                              void* d_out, int out_size, void* d_ws, size_t ws_size,
                              hipStream_t stream) {
  const float* x    = (const float*)d_in[0];
  const float* w_ih = (const float*)d_in[1];
  const float* w_hh = (const float*)d_in[2];
  const float* b_ih = (const float*)d_in[3];
  const float* b_hh = (const float*)d_in[4];
  const float* w_fc = (const float*)d_in[5];
  const float* b_fc = (const float*)d_in[6];
  float* out = (float*)d_out;
  Bar* bars = (Bar*)d_ws;
  _Float16* hbuf = (_Float16*)((char*)d_ws + HB_OFF);

  hipLaunchKernelGGL(init_kernel, dim3(256), dim3(256), 0, stream, (int*)d_ws, out);
  hipLaunchKernelGGL(lstm_persist, dim3(NGRP * NUB), dim3(512), 0, stream,
                     x, w_ih, w_hh, b_ih, b_hh, w_fc, b_fc, out, hbuf, bars);
}

// Round 5
// 8424.760 us; speedup vs baseline: 1.2029x; 1.2029x over previous
//
#include <hip/hip_runtime.h>

typedef _Float16 f16x8 __attribute__((ext_vector_type(8)));
typedef float    f32x4 __attribute__((ext_vector_type(4)));
typedef unsigned long long u64;

constexpr int BATCH = 1024;
constexpr int HDIM  = 512;
constexpr int TENC  = 512;
constexpr int PRED  = 48;
constexpr int STEPS = TENC + PRED - 1;   // 559 cell steps
constexpr int NGRP  = 32;                // independent batch groups
constexpr int GBAT  = 32;                // batches per group
constexpr int NUB   = 8;                 // unit-blocks per group
constexpr int UBU   = 64;                // units per block
constexpr int HB_OFF = 32768;            // hbuf offset in ws (bytes); flags below

__global__ void init_kernel(int* wsi, float* out) {
  int idx = blockIdx.x * blockDim.x + threadIdx.x;
  int stride = gridDim.x * blockDim.x;
  const int nws = (HB_OFF + BATCH * HDIM * 2) / 4;  // flags + hbuf[0]
  for (int i = idx; i < nws; i += stride) wsi[i] = 0;
  for (int i = idx; i < BATCH * PRED; i += stride) out[i] = 0.f;
}

// 512 threads = 8 waves, pinned 2 waves/EU (256-VGPR budget — R4's compiler
// chose 128 and shuffled weights through AGPR/scratch: VALUBusy 62%).
// Wave pair (w, w^4): same 16-unit n-tile (tile=w&3), K split (half=w>>2).
// Pair exchanges complementary m-tile partials via red[wid][nt][lane]
// (lane-stride 16B, conflict-free b128 — R4's [wid][lane][nt] was 32-way).
// Cross-block sync: per-block monotonic flag (own 64B line), stored after
// vmcnt(0) drain; consumers poll all 8 flags with one wave-load + ballot.
__global__ __attribute__((amdgpu_flat_work_group_size(512, 512),
                          amdgpu_waves_per_eu(2, 2)))
void lstm_persist(
    const float* __restrict__ x,
    const float* __restrict__ w_ih,
    const float* __restrict__ w_hh,
    const float* __restrict__ b_ih,
    const float* __restrict__ b_hh,
    const float* __restrict__ w_fc,
    const float* __restrict__ b_fc,
    float* __restrict__ out,          // [1024][48] fp32; also decode input
    _Float16* __restrict__ hbuf,      // [2][1024][512] fp16 ping-pong
    unsigned* __restrict__ flags)     // [32][8] step counters, 64B apart
{
  const int bid  = blockIdx.x;
  const int grp  = bid & (NGRP - 1);  // group's 8 blocks on one XCD (perf only)
  const int ub   = bid >> 5;
  const int tid  = threadIdx.x;
  const int wid  = tid >> 6;          // 0..7
  const int tile = wid & 3;           // n-tile (16 units)
  const int half = wid >> 2;          // k-half AND owned m-tile
  const int lane = tid & 63;
  const int quad = lane >> 4;
  const int lcol = lane & 15;
  const int b0   = grp * GBAT;
  const int myu  = ub * UBU + tile * 16 + lcol;

  __shared__ __align__(16) _Float16 hs[GBAT][520];   // 33.3 KB
  __shared__ f32x4 red[8][4][64];                    // 32 KB, lane fastest dim

  // ---- one-time: weight B-frags for this wave's kc half (128 VGPR) ----
  f16x8 wf[4][8];
  float wih[4], bias[4];
#pragma unroll
  for (int nt = 0; nt < 4; ++nt) {
    const int j = nt * HDIM + myu;
    wih[nt]  = w_ih[j];
    bias[nt] = b_ih[j] + b_hh[j];
#pragma unroll
    for (int kc = 0; kc < 8; ++kc) {
      const int kcg = half * 8 + kc;
      const float* s = w_hh + (size_t)j * HDIM + kcg * 32 + quad * 8;
      f16x8 v;
#pragma unroll
      for (int i = 0; i < 8; ++i) v[i] = (_Float16)s[i];
      wf[nt][kc] = v;
    }
  }
  const float wfc = w_fc[myu];
  const float bfc = b_fc[0];

  float cst[4];                        // 4 cells/lane (own m-tile)
#pragma unroll
  for (int r = 0; r < 4; ++r) cst[r] = 0.f;

  unsigned* gflags = flags + grp * NUB * 16;   // 8 flags, 64B apart
  unsigned* myflag = gflags + ub * 16;

  for (int t = 0; t < STEPS; ++t) {
    const _Float16* hcur = hbuf + (size_t)(t & 1) * BATCH * HDIM;
    _Float16*       hnxt = hbuf + (size_t)((t + 1) & 1) * BATCH * HDIM;

    // ---- encoder x_t can load before the sync (read-only input) ----
    float xts[4];
    if (t < TENC) {
#pragma unroll
      for (int r = 0; r < 4; ++r) {
        const int b = b0 + half * 16 + quad * 4 + r;
        xts[r] = x[(size_t)b * TENC + t];
      }
    }

    // ---- wait: all 8 producers published step t (wave 0 polls) ----
    if (t > 0 && wid == 0) {
      for (;;) {
        unsigned v = __hip_atomic_load(gflags + (lane & 7) * 16,
                                       __ATOMIC_RELAXED, __HIP_MEMORY_SCOPE_AGENT);
        if (__ballot(v >= (unsigned)t) == ~0ull) break;
      }
    }
    __syncthreads();

    // ---- decode feedback (written by step t-1 fc atomics, now visible) ----
    if (t >= TENC) {
#pragma unroll
      for (int r = 0; r < 4; ++r) {
        const int b = b0 + half * 16 + quad * 4 + r;
        xts[r] = __hip_atomic_load(&out[b * PRED + (t - TENC)],
                                   __ATOMIC_RELAXED, __HIP_MEMORY_SCOPE_AGENT);
      }
    }

    // ---- stage h tile into LDS (coherent 8B loads, all 8 in flight) ----
    u64 tmp[8];
#pragma unroll
    for (int i = 0; i < 8; ++i) {
      const int e   = tid + i * 512;      // 4096 8B-chunks
      const int row = e >> 7;
      const int c   = e & 127;
      tmp[i] = __hip_atomic_load(
          (const u64*)(hcur + (size_t)(b0 + row) * HDIM) + c,
          __ATOMIC_RELAXED, __HIP_MEMORY_SCOPE_AGENT);
    }
#pragma unroll
    for (int i = 0; i < 8; ++i) {
      const int e   = tid + i * 512;
      const int row = e >> 7;
      const int c   = e & 127;
      *reinterpret_cast<u64*>(&hs[row][c * 4]) = tmp[i];
    }
    __syncthreads();

    // ---- partial GEMM over this wave's kc half ----
    f32x4 acc[2][4];
#pragma unroll
    for (int mt = 0; mt < 2; ++mt)
#pragma unroll
      for (int nt = 0; nt < 4; ++nt) acc[mt][nt] = (f32x4){0.f, 0.f, 0.f, 0.f};

#pragma unroll
    for (int kc = 0; kc < 8; ++kc) {
      const int kcg = half * 8 + kc;
      f16x8 a0 = *reinterpret_cast<const f16x8*>(&hs[lcol][kcg * 32 + quad * 8]);
      f16x8 a1 = *reinterpret_cast<const f16x8*>(&hs[16 + lcol][kcg * 32 + quad * 8]);
#pragma unroll
      for (int nt = 0; nt < 4; ++nt) {
        acc[0][nt] = __builtin_amdgcn_mfma_f32_16x16x32_f16(a0, wf[nt][kc], acc[0][nt], 0, 0, 0);
        acc[1][nt] = __builtin_amdgcn_mfma_f32_16x16x32_f16(a1, wf[nt][kc], acc[1][nt], 0, 0, 0);
      }
    }

    // ---- pair exchange: hand partner the m-tile it owns ----
#pragma unroll
    for (int nt = 0; nt < 4; ++nt) red[wid][nt][lane] = acc[half ^ 1][nt];
    __syncthreads();
    f32x4 accf[4];
#pragma unroll
    for (int nt = 0; nt < 4; ++nt)
      accf[nt] = acc[half][nt] + red[wid ^ 4][nt][lane];

    // ---- cell update: 4 cells/lane (C-layout col=lcol, row=quad*4+r) ----
    float hnew[4];
#pragma unroll
    for (int r = 0; r < 4; ++r) {
      const float xt = xts[r];
      const float gi = accf[0][r] + xt * wih[0] + bias[0];
      const float gf = accf[1][r] + xt * wih[1] + bias[1];
      const float gg = accf[2][r] + xt * wih[2] + bias[2];
      const float go = accf[3][r] + xt * wih[3] + bias[3];
      const float si = 1.f / (1.f + __expf(-gi));
      const float sf = 1.f / (1.f + __expf(-gf));
      const float so = 1.f / (1.f + __expf(-go));
      const float tg = 1.f - 2.f / (1.f + __expf(2.f * gg));
      const float cn = sf * cst[r] + si * tg;
      cst[r] = cn;
      const float tc = 1.f - 2.f / (1.f + __expf(2.f * cn));
      const float hn = so * tc;
      hnew[r] = hn;

      // pack 4 adjacent units across lanes -> one 8B coherent store
      const unsigned short hb = __builtin_bit_cast(unsigned short, (_Float16)hn);
      const unsigned v0  = hb;
      const unsigned o0  = (unsigned)__shfl_xor((int)v0, 1);
      const unsigned p01 = (lcol & 1) ? ((v0 << 16) | o0) : ((o0 << 16) | v0);
      const unsigned q   = (unsigned)__shfl_xor((int)p01, 2);
      const u64 p4 = (lcol & 2) ? (((u64)p01 << 32) | (u64)q)
                                : (((u64)q << 32) | (u64)p01);
      if ((lcol & 3) == r) {
        const int b = b0 + half * 16 + quad * 4 + r;
        _Float16* dst = hnxt + (size_t)b * HDIM + (ub * UBU + tile * 16 + (lcol & ~3));
        __hip_atomic_store((u64*)dst, p4, __ATOMIC_RELAXED, __HIP_MEMORY_SCOPE_AGENT);
      }
    }

    // ---- fc(h) for decode steps (drained before flag store) ----
    if (t >= TENC - 1) {
      const int p = t - (TENC - 1);
#pragma unroll
      for (int r = 0; r < 4; ++r) {
        float v = hnew[r] * wfc;
        v += __shfl_xor(v, 1);
        v += __shfl_xor(v, 2);
        v += __shfl_xor(v, 4);
        v += __shfl_xor(v, 8);
        if (lcol == 0) {
          const int b = b0 + half * 16 + quad * 4 + r;
          // bias exactly once per batch: (ub0,tile0) wave of the owning half
          const float add = v + ((ub == 0 && tile == 0) ? bfc : 0.f);
          atomicAdd(&out[b * PRED + p], add);
        }
      }
    }

    // ---- publish: drain own stores, block-join, single flag store ----
    asm volatile("s_waitcnt vmcnt(0)" ::: "memory");
    __syncthreads();
    if (tid == 0)
      __hip_atomic_store(myflag, (unsigned)(t + 1),
                         __ATOMIC_RELAXED, __HIP_MEMORY_SCOPE_AGENT);
  }
}

extern "C" void kernel_launch(void* const* d_in, const int* in_sizes, int n_in,
                              void* d_out, int out_size, void* d_ws, size_t ws_size,
                              hipStream_t stream) {
  const float* x    = (const float*)d_in[0];
  const float* w_ih = (const float*)d_in[1];
  const float* w_hh = (const float*)d_in[2];
  const float* b_ih = (const float*)d_in[3];
  const float* b_hh = (const float*)d_in[4];
  const float* w_fc = (const float*)d_in[5];
  const float* b_fc = (const float*)d_in[6];
  float* out = (float*)d_out;
  unsigned* flags = (unsigned*)d_ws;
  _Float16* hbuf = (_Float16*)((char*)d_ws + HB_OFF);

  hipLaunchKernelGGL(init_kernel, dim3(256), dim3(256), 0, stream, (int*)d_ws, out);
  hipLaunchKernelGGL(lstm_persist, dim3(NGRP * NUB), dim3(512), 0, stream,
                     x, w_ih, w_hh, b_ih, b_hh, w_fc, b_fc, out, hbuf, flags);
}

// Round 6
// 3589.717 us; speedup vs baseline: 2.8231x; 2.3469x over previous
//
#include <hip/hip_runtime.h>

typedef _Float16 f16x8 __attribute__((ext_vector_type(8)));
typedef float    f32x4 __attribute__((ext_vector_type(4)));
typedef unsigned long long u64;

constexpr int BATCH = 1024;
constexpr int HDIM  = 512;
constexpr int TENC  = 512;
constexpr int PRED  = 48;
constexpr int STEPS = TENC + PRED - 1;   // 559 cell steps
constexpr int NGRP  = 32;                // independent batch groups
constexpr int GBAT  = 32;                // batches per group
constexpr int NUB   = 8;                 // unit-blocks per group
constexpr int UBU   = 64;                // units per block
constexpr int HB_OFF = 32768;            // hbuf offset in ws; flags live below

__global__ void init_kernel(int* wsi, float* out) {
  int idx = blockIdx.x * blockDim.x + threadIdx.x;
  int stride = gridDim.x * blockDim.x;
  const int nws = (HB_OFF + BATCH * HDIM * 2) / 4;  // flags + hbuf[0]
  for (int i = idx; i < nws; i += stride) wsi[i] = 0;
  for (int i = idx; i < BATCH * PRED; i += stride) out[i] = 0.f;
}

// Coherent 16B load: sc0 sc1 -> bypass L1/L2, read at the device coherence
// point (needed: producer blocks may be on other XCDs). __hip_atomic_load
// caps at 8B; this is the 16B equivalent. Caller must s_waitcnt vmcnt(0)
// before using the result (done in bulk after issuing all loads).
static __device__ __forceinline__ f16x8 load16_coh(const _Float16* p) {
  f16x8 v;
  asm volatile("global_load_dwordx4 %0, %1, off sc0 sc1"
               : "=v"(v) : "v"((u64)p) : "memory");
  return v;
}

// R2 structure (proven 3.77ms): 256 threads = 4 waves = 1 wave/EU, each wave
// owns a 16-unit n-tile with FULL-K weights in regs (arch+AGPR, ~340 total;
// MFMA reads B from AGPR natively on gfx950). K-split variants (R4/R5)
// forced a 128-VGPR allocation + spill code: VALUBusy 62-74%. Don't split.
// New vs R2: per-block monotonic flag barrier (single store / parallel poll,
// no count-atomic round trip), fine-grained per-producer waits (wave w polls
// producers 2w,2w+1 and stages their slices as they land), 16B sc0sc1
// staging loads, x prefetched before the wait.
__global__ __launch_bounds__(256, 1) void lstm_persist(
    const float* __restrict__ x,
    const float* __restrict__ w_ih,
    const float* __restrict__ w_hh,
    const float* __restrict__ b_ih,
    const float* __restrict__ b_hh,
    const float* __restrict__ w_fc,
    const float* __restrict__ b_fc,
    float* __restrict__ out,          // [1024][48] fp32; also decode input
    _Float16* __restrict__ hbuf,      // [2][1024][512] fp16 ping-pong
    unsigned* __restrict__ flags)     // [32][8] step counters, 64B apart
{
  const int bid  = blockIdx.x;
  const int grp  = bid & (NGRP - 1);  // group's 8 blocks on one XCD (perf only)
  const int ub   = bid >> 5;
  const int tid  = threadIdx.x;
  const int wid  = tid >> 6;          // wave 0..3 = n-tile
  const int lane = tid & 63;
  const int quad = lane >> 4;
  const int lcol = lane & 15;
  const int b0   = grp * GBAT;
  const int myu  = ub * UBU + wid * 16 + lcol;

  __shared__ __align__(16) _Float16 hs[GBAT][520];   // 33.3 KB

  // ---- one-time: full-K weight B-frags (n=lane&15, k=kc*32+quad*8+j) ----
  f16x8 wf[4][16];
  float wih[4], bias[4];
#pragma unroll
  for (int nt = 0; nt < 4; ++nt) {
    const int j = nt * HDIM + myu;
    wih[nt]  = w_ih[j];
    bias[nt] = b_ih[j] + b_hh[j];
#pragma unroll
    for (int kc = 0; kc < 16; ++kc) {
      const float* s = w_hh + (size_t)j * HDIM + kc * 32 + quad * 8;
      f16x8 v;
#pragma unroll
      for (int i = 0; i < 8; ++i) v[i] = (_Float16)s[i];
      wf[nt][kc] = v;
    }
  }
  const float wfc = w_fc[myu];
  const float bfc = b_fc[0];

  float cst[2][4];
#pragma unroll
  for (int mt = 0; mt < 2; ++mt)
#pragma unroll
    for (int r = 0; r < 4; ++r) cst[mt][r] = 0.f;

  unsigned* gflags = flags + grp * NUB * 16;   // 8 flags, 64B apart
  unsigned* myflag = gflags + ub * 16;
  const int p0 = 2 * wid, p1 = 2 * wid + 1;    // this wave's producers

  for (int t = 0; t < STEPS; ++t) {
    const _Float16* hcur = hbuf + (size_t)(t & 1) * BATCH * HDIM;
    _Float16*       hnxt = hbuf + (size_t)((t + 1) & 1) * BATCH * HDIM;

    // ---- encoder x_t: load before any waiting (read-only input) ----
    float xts[2][4];
    if (t < TENC) {
#pragma unroll
      for (int mt = 0; mt < 2; ++mt)
#pragma unroll
        for (int r = 0; r < 4; ++r) {
          const int b = b0 + mt * 16 + quad * 4 + r;
          xts[mt][r] = x[(size_t)b * TENC + t];
        }
    }

    // ---- fine-grained wait + stage: producer p's slice = units [64p,64p+64)
    // slice: 32 rows x 128B; lane does 4 x 16B (chunk = i*64+lane)
    f16x8 tmp[8];
    if (t > 0) {
      while (__hip_atomic_load(gflags + p0 * 16, __ATOMIC_RELAXED,
                               __HIP_MEMORY_SCOPE_AGENT) < (unsigned)t) {}
    }
#pragma unroll
    for (int i = 0; i < 4; ++i) {
      const int chunk = i * 64 + lane;
      const int row = chunk >> 3, c16 = chunk & 7;
      tmp[i] = load16_coh(hcur + (size_t)(b0 + row) * HDIM + p0 * 64 + c16 * 8);
    }
    if (t > 0) {
      while (__hip_atomic_load(gflags + p1 * 16, __ATOMIC_RELAXED,
                               __HIP_MEMORY_SCOPE_AGENT) < (unsigned)t) {}
    }
#pragma unroll
    for (int i = 0; i < 4; ++i) {
      const int chunk = i * 64 + lane;
      const int row = chunk >> 3, c16 = chunk & 7;
      tmp[4 + i] = load16_coh(hcur + (size_t)(b0 + row) * HDIM + p1 * 64 + c16 * 8);
    }
    asm volatile("s_waitcnt vmcnt(0)" ::: "memory");
#pragma unroll
    for (int i = 0; i < 8; ++i) {
      const int p = (i < 4) ? p0 : p1;
      const int chunk = (i & 3) * 64 + lane;
      const int row = chunk >> 3, c16 = chunk & 7;
      *reinterpret_cast<f16x8*>(&hs[row][p * 64 + c16 * 8]) = tmp[i];
    }
    __syncthreads();   // all 8 slices staged (4 waves x 2 producers)

    // ---- decode feedback (guarded collectively by the 8 flags) ----
    if (t >= TENC) {
#pragma unroll
      for (int mt = 0; mt < 2; ++mt)
#pragma unroll
        for (int r = 0; r < 4; ++r) {
          const int b = b0 + mt * 16 + quad * 4 + r;
          xts[mt][r] = __hip_atomic_load(&out[b * PRED + (t - TENC)],
                                         __ATOMIC_RELAXED, __HIP_MEMORY_SCOPE_AGENT);
        }
    }

    // ---- GEMM: acc[mt][nt] = h(32x512) @ w_tile.T, full K ----
    f32x4 acc[2][4];
#pragma unroll
    for (int mt = 0; mt < 2; ++mt)
#pragma unroll
      for (int nt = 0; nt < 4; ++nt) acc[mt][nt] = (f32x4){0.f, 0.f, 0.f, 0.f};

#pragma unroll
    for (int kc = 0; kc < 16; ++kc) {
      f16x8 a0 = *reinterpret_cast<const f16x8*>(&hs[lcol][kc * 32 + quad * 8]);
      f16x8 a1 = *reinterpret_cast<const f16x8*>(&hs[16 + lcol][kc * 32 + quad * 8]);
#pragma unroll
      for (int nt = 0; nt < 4; ++nt) {
        acc[0][nt] = __builtin_amdgcn_mfma_f32_16x16x32_f16(a0, wf[nt][kc], acc[0][nt], 0, 0, 0);
        acc[1][nt] = __builtin_amdgcn_mfma_f32_16x16x32_f16(a1, wf[nt][kc], acc[1][nt], 0, 0, 0);
      }
    }

    // ---- cell update (C-layout: col=lcol, row=quad*4+r) ----
    float hnew[2][4];
#pragma unroll
    for (int mt = 0; mt < 2; ++mt) {
#pragma unroll
      for (int r = 0; r < 4; ++r) {
        const int b = b0 + mt * 16 + quad * 4 + r;
        const float xt = xts[mt][r];
        const float gi = acc[mt][0][r] + xt * wih[0] + bias[0];
        const float gf = acc[mt][1][r] + xt * wih[1] + bias[1];
        const float gg = acc[mt][2][r] + xt * wih[2] + bias[2];
        const float go = acc[mt][3][r] + xt * wih[3] + bias[3];
        const float si = 1.f / (1.f + __expf(-gi));
        const float sf = 1.f / (1.f + __expf(-gf));
        const float so = 1.f / (1.f + __expf(-go));
        const float tg = 1.f - 2.f / (1.f + __expf(2.f * gg));
        const float cn = sf * cst[mt][r] + si * tg;
        cst[mt][r] = cn;
        const float tc = 1.f - 2.f / (1.f + __expf(2.f * cn));
        const float hn = so * tc;
        hnew[mt][r] = hn;

        // pack 4 adjacent units across lanes -> one 8B coherent store
        const unsigned short hb = __builtin_bit_cast(unsigned short, (_Float16)hn);
        const unsigned v0  = hb;
        const unsigned o0  = (unsigned)__shfl_xor((int)v0, 1);
        const unsigned p01 = (lcol & 1) ? ((v0 << 16) | o0) : ((o0 << 16) | v0);
        const unsigned q   = (unsigned)__shfl_xor((int)p01, 2);
        const u64 p4 = (lcol & 2) ? (((u64)p01 << 32) | (u64)q)
                                  : (((u64)q << 32) | (u64)p01);
        if ((lcol & 3) == ((mt * 4 + r) & 3)) {
          _Float16* dst = hnxt + (size_t)b * HDIM + (ub * UBU + wid * 16 + (lcol & ~3));
          __hip_atomic_store((u64*)dst, p4, __ATOMIC_RELAXED, __HIP_MEMORY_SCOPE_AGENT);
        }
      }
    }

    // ---- fc(h) for decode steps (drained before flag publish) ----
    if (t >= TENC - 1) {
      const int p = t - (TENC - 1);
#pragma unroll
      for (int mt = 0; mt < 2; ++mt) {
#pragma unroll
        for (int r = 0; r < 4; ++r) {
          float v = hnew[mt][r] * wfc;
          v += __shfl_xor(v, 1);
          v += __shfl_xor(v, 2);
          v += __shfl_xor(v, 4);
          v += __shfl_xor(v, 8);
          if (lcol == 0) {
            const int b = b0 + mt * 16 + quad * 4 + r;
            const float add = v + ((ub == 0 && wid == 0) ? bfc : 0.f);
            atomicAdd(&out[b * PRED + p], add);
          }
        }
      }
    }

    // ---- publish: every wave drains own stores, join, single flag store ----
    asm volatile("s_waitcnt vmcnt(0)" ::: "memory");
    __syncthreads();
    if (tid == 0)
      __hip_atomic_store(myflag, (unsigned)(t + 1),
                         __ATOMIC_RELAXED, __HIP_MEMORY_SCOPE_AGENT);
  }
}

extern "C" void kernel_launch(void* const* d_in, const int* in_sizes, int n_in,
                              void* d_out, int out_size, void* d_ws, size_t ws_size,
                              hipStream_t stream) {
  const float* x    = (const float*)d_in[0];
  const float* w_ih = (const float*)d_in[1];
  const float* w_hh = (const float*)d_in[2];
  const float* b_ih = (const float*)d_in[3];
  const float* b_hh = (const float*)d_in[4];
  const float* w_fc = (const float*)d_in[5];
  const float* b_fc = (const float*)d_in[6];
  float* out = (float*)d_out;
  unsigned* flags = (unsigned*)d_ws;
  _Float16* hbuf = (_Float16*)((char*)d_ws + HB_OFF);

  hipLaunchKernelGGL(init_kernel, dim3(256), dim3(256), 0, stream, (int*)d_ws, out);
  hipLaunchKernelGGL(lstm_persist, dim3(NGRP * NUB), dim3(256), 0, stream,
                     x, w_ih, w_hh, b_ih, b_hh, w_fc, b_fc, out, hbuf, flags);
}